// Round 6
// baseline (1060.550 us; speedup 1.0000x reference)
//
#include <hip/hip_runtime.h>
#include <hip/hip_bf16.h>

#define L_ 2
#define T_ 512
#define B_ 128
#define F_ 4
#define H_ 256
#define QSIGN_MASK 0x5390

typedef __attribute__((ext_vector_type(8))) short short8;
typedef __attribute__((ext_vector_type(4))) float f32x4;

// Mailbox: layer-0 normalized output, bf16x4 packed in one qword per (t, b).
// Norm-1 vector => at least one |comp| >= 0.5 => qword is never 0. Zeroed each call.
__device__ unsigned long long g_inter_q[T_][B_];

__global__ void zero_inter() {
  ((unsigned long long*)g_inter_q)[blockIdx.x * 256 + threadIdx.x] = 0ull;
}

__device__ __forceinline__ unsigned f2bf(float f) {
  unsigned u = __float_as_uint(f);
  return (u + 0x7fff + ((u >> 16) & 1)) >> 16;
}
__device__ __forceinline__ float bfs(unsigned v) { return __uint_as_float(v << 16); }
__device__ __forceinline__ float fast_sigmoid(float x) { return 1.f / (1.f + __expf(-x)); }
__device__ __forceinline__ float fast_tanh(float x) {
  float a = fabsf(x), e = __expf(2.f * a);
  return copysignf(1.f - 2.f / (e + 1.f), x);
}
__device__ __forceinline__ unsigned long long pack4bf(float a, float b, float c, float d) {
  return (unsigned long long)f2bf(a)
       | ((unsigned long long)f2bf(b) << 16)
       | ((unsigned long long)f2bf(c) << 32)
       | ((unsigned long long)f2bf(d) << 48);
}

union FragU { short8 v; uint4 u; };

// Grid = 64 WGs x 512 threads. blockIdx<32: producer (layer 0, batch group bg);
// blockIdx>=32: consumer (layer 1, same bg). Mailbox handoff via value-flag
// relaxed 8B atomics (no fences). MFMA rows = (q,b); B frags persistent in regs.
// Wave duties: wave 0 lanes 0-3 = x load (producer) / mailbox poll (consumer),
// depth-2 prefetch into ring-4 sh_x; waves 4-7 = projection reduce (producer).
__launch_bounds__(512, 2)
__global__ void qlstm_fused(const float* __restrict__ x_in,
                            const float* __restrict__ uhr, const float* __restrict__ uhi,
                            const float* __restrict__ uhj, const float* __restrict__ uhk,
                            const float* __restrict__ wxr, const float* __restrict__ wxi,
                            const float* __restrict__ wxj, const float* __restrict__ wxk,
                            const float* __restrict__ wxb_all,
                            const float* __restrict__ fcw_all, const float* __restrict__ fcb_all,
                            float* __restrict__ out_final)
{
  __shared__ unsigned short sh_h[4][272];   // h state bf16, row stride 544 B
  __shared__ float sh_pre[4][256][4];       // pre-activations [b][col][gate]
  __shared__ float sh_x[4][4][4];           // ring-4 x buffers [t&3][b][f]

  const int t     = threadIdx.x;
  const int role  = blockIdx.x >> 5;        // 0 = layer0 producer, 1 = layer1 consumer
  const int bg    = blockIdx.x & 31;
  const int layer = role;
  const int lane  = t & 63;
  const int wv    = t >> 6;
  const int sub   = lane & 15;
  const int quad  = lane >> 4;
  const int g     = wv >> 1;
  const int uh    = wv & 1;
  const int col   = t & 255;
  const int bg0   = bg * 4;

  const float* wb = wxb_all + layer * 4 * H_;
  const float* fw = fcw_all + layer * H_ * F_;
  const float* fb = fcb_all + layer * F_;

  for (int i = t; i < 4 * 272; i += 512) ((unsigned short*)sh_h)[i] = 0;

  // ---- persistent B fragments [d][ks][un] (raw component blocks, bf16) ----
  FragU Bf[16];
  {
    const float* Cc[4] = {uhr, uhi, uhj, uhk};
    #pragma unroll
    for (int d = 0; d < 4; ++d)
      #pragma unroll
      for (int ks = 0; ks < 2; ++ks)
        #pragma unroll
        for (int un = 0; un < 2; ++un) {
          const float* src = Cc[d] + (size_t)((layer * 4 + g) * 64 + ks * 32 + quad * 8) * 64
                             + uh * 32 + un * 16 + sub;
          FragU f;
          #pragma unroll
          for (int j = 0; j < 8; ++j) f.v[j] = (short)f2bf(src[j * 64]);
          Bf[d * 4 + ks * 2 + un] = f;
        }
  }
  // ---- per-lane sign masks + A-read bases: A rows m = (q=sub>>2, b=sub&3) ----
  unsigned smask[4];
  int abase[4];
  {
    const int ql = sub >> 2, bq = sub & 3;
    #pragma unroll
    for (int d = 0; d < 4; ++d) {
      int a = ql ^ d;
      smask[d] = ((QSIGN_MASK >> (a * 4 + ql)) & 1) ? 0x80008000u : 0u;
      abase[d] = bq * 544 + ((a * 64 + quad * 8) << 1);
    }
  }
  // ---- phase-B constants: signed-expanded Wx + bias for this thread's col ----
  float wxf[4][4], wbv[4];
  {
    const float* X[4] = {wxr, wxi, wxj, wxk};
    int q = col >> 6, c = col & 63;
    #pragma unroll
    for (int gg = 0; gg < 4; ++gg) {
      wbv[gg] = wb[gg * 256 + col];
      #pragma unroll
      for (int a = 0; a < 4; ++a) {
        float v = X[a ^ q][(layer * 4 + gg) * 64 + c];
        if ((QSIGN_MASK >> (a * 4 + q)) & 1) v = -v;
        wxf[gg][a] = v;
      }
    }
  }
  // ---- projection constants: lane handles h indices lane*4..lane*4+3 ----
  float4 fwr[4];
  #pragma unroll
  for (int j = 0; j < 4; ++j) fwr[j] = *(const float4*)(fw + (lane * 4 + j) * 4);
  const float fb0 = fb[0], fb1 = fb[1], fb2 = fb[2], fb3 = fb[3];

  // ---- prologue: x[0], x[1] into ring ----
  if (t < 4) {
    #pragma unroll
    for (int s0 = 0; s0 < 2; ++s0) {
      if (role == 0) {
        *(float4*)&sh_x[s0][t][0] =
            *(const float4*)(x_in + (size_t)((bg0 + t) * T_ + s0) * F_);
      } else {
        unsigned long long v;
        while ((v = __hip_atomic_load(&g_inter_q[s0][bg0 + t], __ATOMIC_RELAXED,
                                      __HIP_MEMORY_SCOPE_AGENT)) == 0ull)
          __builtin_amdgcn_s_sleep(1);
        float* dx = &sh_x[s0][t][0];
        dx[0] = bfs((unsigned)(v & 0xffff));
        dx[1] = bfs((unsigned)((v >> 16) & 0xffff));
        dx[2] = bfs((unsigned)((v >> 32) & 0xffff));
        dx[3] = bfs((unsigned)((v >> 48) & 0xffff));
      }
    }
  }
  float cst0 = 0.f, cst1 = 0.f;
  __syncthreads();

  const char* hbB = (const char*)sh_h;

  for (int step = 0; step < T_; ++step) {
    // ---- phase A: prefetch x[step+2] (wave 0), producer projection (waves 4-7) ----
    if (t < 4 && step + 2 < T_) {
      if (role == 0) {
        *(float4*)&sh_x[(step + 2) & 3][t][0] =
            *(const float4*)(x_in + (size_t)((bg0 + t) * T_ + step + 2) * F_);
      } else {
        unsigned long long v;
        while ((v = __hip_atomic_load(&g_inter_q[step + 2][bg0 + t], __ATOMIC_RELAXED,
                                      __HIP_MEMORY_SCOPE_AGENT)) == 0ull)
          __builtin_amdgcn_s_sleep(1);
        float* dx = &sh_x[(step + 2) & 3][t][0];
        dx[0] = bfs((unsigned)(v & 0xffff));
        dx[1] = bfs((unsigned)((v >> 16) & 0xffff));
        dx[2] = bfs((unsigned)((v >> 32) & 0xffff));
        dx[3] = bfs((unsigned)((v >> 48) & 0xffff));
      }
    }
    if (role == 0 && step > 0 && wv >= 4) {
      const int b = wv & 3;
      unsigned long long hv = *(const unsigned long long*)((const char*)sh_h + b * 544 + lane * 8);
      float h0 = bfs((unsigned)(hv & 0xffff));
      float h1 = bfs((unsigned)((hv >> 16) & 0xffff));
      float h2 = bfs((unsigned)((hv >> 32) & 0xffff));
      float h3 = bfs((unsigned)((hv >> 48) & 0xffff));
      float p0 = h0 * fwr[0].x + h1 * fwr[1].x + h2 * fwr[2].x + h3 * fwr[3].x;
      float p1 = h0 * fwr[0].y + h1 * fwr[1].y + h2 * fwr[2].y + h3 * fwr[3].y;
      float p2 = h0 * fwr[0].z + h1 * fwr[1].z + h2 * fwr[2].z + h3 * fwr[3].z;
      float p3 = h0 * fwr[0].w + h1 * fwr[1].w + h2 * fwr[2].w + h3 * fwr[3].w;
      #pragma unroll
      for (int off = 32; off; off >>= 1) {
        p0 += __shfl_down(p0, off, 64); p1 += __shfl_down(p1, off, 64);
        p2 += __shfl_down(p2, off, 64); p3 += __shfl_down(p3, off, 64);
      }
      if (lane == 0) {
        p0 += fb0; p1 += fb1; p2 += fb2; p3 += fb3;
        float inv = 1.f / fmaxf(sqrtf(p0*p0 + p1*p1 + p2*p2 + p3*p3), 1e-12f);
        __hip_atomic_store(&g_inter_q[step - 1][bg0 + b],
                           pack4bf(p0 * inv, p1 * inv, p2 * inv, p3 * inv),
                           __ATOMIC_RELAXED, __HIP_MEMORY_SCOPE_AGENT);
      }
    }

    // ---- MFMA: rows (q,b); chains over d, 4 independent accumulators ----
    f32x4 acc[4];   // [ks*2+un]
    #pragma unroll
    for (int i = 0; i < 4; ++i) { f32x4 z = {0.f,0.f,0.f,0.f}; acc[i] = z; }
    #pragma unroll
    for (int ks = 0; ks < 2; ++ks) {
      #pragma unroll
      for (int d = 0; d < 4; ++d) {
        FragU A;
        A.u = *(const uint4*)(hbB + abase[d] + ks * 64);
        A.u.x ^= smask[d]; A.u.y ^= smask[d]; A.u.z ^= smask[d]; A.u.w ^= smask[d];
        acc[ks*2+0] = __builtin_amdgcn_mfma_f32_16x16x32_bf16(A.v, Bf[d*4+ks*2+0].v, acc[ks*2+0], 0, 0, 0);
        acc[ks*2+1] = __builtin_amdgcn_mfma_f32_16x16x32_bf16(A.v, Bf[d*4+ks*2+1].v, acc[ks*2+1], 0, 0, 0);
      }
    }
    // C/D: col=sub, row=quad*4+reg -> (q=quad, b=reg)
    #pragma unroll
    for (int un = 0; un < 2; ++un) {
      int cc = quad * 64 + uh * 32 + un * 16 + sub;
      #pragma unroll
      for (int r = 0; r < 4; ++r)
        sh_pre[r][cc][g] = acc[0*2+un][r] + acc[1*2+un][r];
    }
    __syncthreads();   // barrier 1

    // ---- phase B: thread (b=(t>>8)*2+e, col) -> gates, state, h ----
    #pragma unroll
    for (int e = 0; e < 2; ++e) {
      const int b = (t >> 8) * 2 + e;
      float4 P  = *(const float4*)&sh_pre[b][col][0];
      float4 xv = *(const float4*)&sh_x[step & 3][b][0];
      float pf = P.x + wbv[0] + xv.x*wxf[0][0] + xv.y*wxf[0][1] + xv.z*wxf[0][2] + xv.w*wxf[0][3];
      float pi = P.y + wbv[1] + xv.x*wxf[1][0] + xv.y*wxf[1][1] + xv.z*wxf[1][2] + xv.w*wxf[1][3];
      float po = P.z + wbv[2] + xv.x*wxf[2][0] + xv.y*wxf[2][1] + xv.z*wxf[2][2] + xv.w*wxf[2][3];
      float pc = P.w + wbv[3] + xv.x*wxf[3][0] + xv.y*wxf[3][1] + xv.z*wxf[3][2] + xv.w*wxf[3][3];
      float fg = fast_sigmoid(pf), ig = fast_sigmoid(pi), og = fast_sigmoid(po);
      float cv = fast_tanh(pc);
      float cs = (e == 0) ? cst0 : cst1;
      cs = ig * cv + fg * cs;
      if (e == 0) cst0 = cs; else cst1 = cs;
      float h = og * fast_tanh(cs);
      sh_h[b][col] = (unsigned short)f2bf(h);
    }
    __syncthreads();   // barrier 2
  }

  // ---- epilogue: projection of h[T-1] (waves 4-7) ----
  if (wv >= 4) {
    const int b = wv & 3;
    unsigned long long hv = *(const unsigned long long*)((const char*)sh_h + b * 544 + lane * 8);
    float h0 = bfs((unsigned)(hv & 0xffff));
    float h1 = bfs((unsigned)((hv >> 16) & 0xffff));
    float h2 = bfs((unsigned)((hv >> 32) & 0xffff));
    float h3 = bfs((unsigned)((hv >> 48) & 0xffff));
    float p0 = h0 * fwr[0].x + h1 * fwr[1].x + h2 * fwr[2].x + h3 * fwr[3].x;
    float p1 = h0 * fwr[0].y + h1 * fwr[1].y + h2 * fwr[2].y + h3 * fwr[3].y;
    float p2 = h0 * fwr[0].z + h1 * fwr[1].z + h2 * fwr[2].z + h3 * fwr[3].z;
    float p3 = h0 * fwr[0].w + h1 * fwr[1].w + h2 * fwr[2].w + h3 * fwr[3].w;
    #pragma unroll
    for (int off = 32; off; off >>= 1) {
      p0 += __shfl_down(p0, off, 64); p1 += __shfl_down(p1, off, 64);
      p2 += __shfl_down(p2, off, 64); p3 += __shfl_down(p3, off, 64);
    }
    if (lane == 0) {
      p0 += fb0; p1 += fb1; p2 += fb2; p3 += fb3;
      float inv = 1.f / fmaxf(sqrtf(p0*p0 + p1*p1 + p2*p2 + p3*p3), 1e-12f);
      if (role == 0) {
        __hip_atomic_store(&g_inter_q[T_ - 1][bg0 + b],
                           pack4bf(p0 * inv, p1 * inv, p2 * inv, p3 * inv),
                           __ATOMIC_RELAXED, __HIP_MEMORY_SCOPE_AGENT);
      } else {
        *(float4*)(out_final + (bg0 + b) * F_) =
            make_float4(p0 * inv, p1 * inv, p2 * inv, p3 * inv);
      }
    }
  }
}

extern "C" void kernel_launch(void* const* d_in, const int* in_sizes, int n_in,
                              void* d_out, int out_size, void* d_ws, size_t ws_size,
                              hipStream_t stream) {
  const float* x   = (const float*)d_in[0];
  const float* wxr = (const float*)d_in[1];
  const float* wxi = (const float*)d_in[2];
  const float* wxj = (const float*)d_in[3];
  const float* wxk = (const float*)d_in[4];
  const float* wxb = (const float*)d_in[5];
  const float* uhr = (const float*)d_in[6];
  const float* uhi = (const float*)d_in[7];
  const float* uhj = (const float*)d_in[8];
  const float* uhk = (const float*)d_in[9];
  const float* fcw = (const float*)d_in[10];
  const float* fcb = (const float*)d_in[11];
  float* out = (float*)d_out;

  zero_inter<<<dim3(T_ * B_ / 256), dim3(256), 0, stream>>>();
  qlstm_fused<<<dim3(64), dim3(512), 0, stream>>>(
      x, uhr, uhi, uhj, uhk, wxr, wxi, wxj, wxk, wxb, fcw, fcb, out);
}

// Round 7
// 968.936 us; speedup vs baseline: 1.0946x; 1.0946x over previous
//
#include <hip/hip_runtime.h>

#define L_ 2
#define T_ 512
#define B_ 128
#define F_ 4
#define H_ 256
#define QSIGN_MASK 0x5390

typedef __attribute__((ext_vector_type(8))) short short8;
typedef __attribute__((ext_vector_type(4))) float f32x4;

// Mailbox: layer-0 normalized output, bf16x4 packed per (t,b); norm-1 => nonzero.
__device__ unsigned long long g_inter_q[T_][B_];

__global__ void zero_inter() {
  ((unsigned long long*)g_inter_q)[blockIdx.x * 256 + threadIdx.x] = 0ull;
}

__device__ __forceinline__ unsigned f2bf(float f) {
  unsigned u = __float_as_uint(f);
  return (u + 0x7fff + ((u >> 16) & 1)) >> 16;
}
__device__ __forceinline__ float bfl(unsigned v) { return __uint_as_float(v << 16); }
__device__ __forceinline__ float bfh(unsigned v) { return __uint_as_float(v & 0xffff0000u); }
__device__ __forceinline__ float fast_sigmoid(float x) { return 1.f / (1.f + __expf(-x)); }
__device__ __forceinline__ float fast_tanh(float x) {
  float a = fabsf(x), e = __expf(2.f * a);
  return copysignf(1.f - 2.f / (e + 1.f), x);
}
__device__ __forceinline__ unsigned long long pack4bf(float a, float b, float c, float d) {
  return (unsigned long long)f2bf(a)
       | ((unsigned long long)f2bf(b) << 16)
       | ((unsigned long long)f2bf(c) << 32)
       | ((unsigned long long)f2bf(d) << 48);
}

union FragU { short8 v; uint4 u; unsigned w[4]; };

// Grid = 64 WGs x 768 threads (12 waves). blockIdx<32: layer-0 producer; else layer-1.
// Waves 0-7: compute. MFMA M=(q,b) 16 rows, N=(g,u): wave wv covers u in [8wv,8wv+8),
//   tile0 = gates {0,1}, tile1 = gates {2,3}. B frags (per-gate raw components) and
//   x-weights persist in registers; bias preloaded into accumulator; x-term is one
//   extra MFMA. Gate gather = intra-wave shfl_xor(8); ONE barrier per step (h publish,
//   double-buffered LDS).
// Waves 8-11 (helper, b = wv-8): projection of h[s-1] (producer every step, consumer
//   only s==T), mailbox publish/poll, x prefetch depth 2 into ring-4 sh_x.
__launch_bounds__(768)
__global__ void qlstm_fused(const float* __restrict__ x_in,
                            const float* __restrict__ uhr, const float* __restrict__ uhi,
                            const float* __restrict__ uhj, const float* __restrict__ uhk,
                            const float* __restrict__ wxr, const float* __restrict__ wxi,
                            const float* __restrict__ wxj, const float* __restrict__ wxk,
                            const float* __restrict__ wxb_all,
                            const float* __restrict__ fcw_all, const float* __restrict__ fcb_all,
                            float* __restrict__ out_final)
{
  __shared__ __align__(16) unsigned short sh_h[2][4][272];  // double-buffered h (bf16)
  __shared__ unsigned long long sh_x[4][4];                 // ring-4 x, 4x bf16 packed

  const int t    = threadIdx.x;
  const int role = blockIdx.x >> 5;
  const int bg   = blockIdx.x & 31;
  const int bg0  = bg * 4;
  const int layer = role;
  const int wv   = t >> 6;
  const int lane = t & 63;
  const int quad = lane >> 4;
  const int sub  = lane & 15;

  const float* wb = wxb_all + layer * 4 * H_;
  const float* fw = fcw_all + layer * H_ * F_;
  const float* fb = fcb_all + layer * F_;

  for (int i = t; i < 2 * 4 * 272; i += 768) ((unsigned short*)sh_h)[i] = 0;

  if (wv < 8) {
    // ================= COMPUTE WAVES =================
    const int qm = sub >> 2;      // A/D row coords: m = qm*4 + bm
    const int bm = sub & 3;
    const int s8 = sub >> 3;      // N coords: n = (g = tg*2+s8, du)
    const int du = sub & 7;
    const int u  = wv * 8 + du;

    // persistent B fragments: [tg][ks] raw component blocks for gate g=tg*2+s8
    FragU Bf[16], Bx[2];
    float bias[2];
    {
      const float* Cc[4] = {uhr, uhi, uhj, uhk};
      const float* Xc[4] = {wxr, wxi, wxj, wxk};
      #pragma unroll
      for (int tg = 0; tg < 2; ++tg) {
        const int g = tg * 2 + s8;
        #pragma unroll
        for (int ks = 0; ks < 8; ++ks) {
          const int d  = ks >> 1;
          const int pp = (ks & 1) * 32 + quad * 8;
          const float* src = Cc[d] + (size_t)((layer * 4 + g) * 64 + pp) * 64 + u;
          FragU f;
          #pragma unroll
          for (int j = 0; j < 8; ++j) f.v[j] = (short)f2bf(src[j * 64]);
          Bf[tg * 8 + ks] = f;
        }
        FragU fx; fx.w[0] = 0; fx.w[1] = 0; fx.w[2] = 0; fx.w[3] = 0;
        if (quad == 0) {
          unsigned e0 = f2bf(Xc[0][(layer * 4 + g) * 64 + u]);
          unsigned e1 = f2bf(Xc[1][(layer * 4 + g) * 64 + u]);
          unsigned e2 = f2bf(Xc[2][(layer * 4 + g) * 64 + u]);
          unsigned e3 = f2bf(Xc[3][(layer * 4 + g) * 64 + u]);
          fx.w[0] = e0 | (e1 << 16);
          fx.w[1] = e2 | (e3 << 16);
        }
        Bx[tg] = fx;
        bias[tg] = wb[g * 256 + quad * 64 + u];
      }
    }
    // sign masks (a = qm ^ d) and A-read byte offsets per ks
    unsigned smask[4], smx[4], xsh[4];
    int aoff[8];
    #pragma unroll
    for (int d = 0; d < 4; ++d) {
      const int a = qm ^ d;
      const bool neg = (QSIGN_MASK >> (a * 4 + qm)) & 1;
      smask[d] = neg ? 0x80008000u : 0u;
      smx[d]   = neg ? 0x8000u : 0u;
      xsh[d]   = 16 * (qm ^ d);
    }
    #pragma unroll
    for (int ks = 0; ks < 8; ++ks)
      aoff[ks] = bm * 544 + (((qm ^ (ks >> 1)) * 64 + (ks & 1) * 32 + quad * 8) << 1);
    const int hw_off = (quad * 64 + u) << 1;   // write col byte offset
    float cs0 = 0.f, cs1 = 0.f;
    __syncthreads();

    for (int s = 0; s <= T_; ++s) {
      if (s < T_) {
        const char* hp = (const char*)sh_h + ((s + 1) & 1) * 2176;  // h[s-1]
        char*       hw = (char*)sh_h + (s & 1) * 2176;              // h[s]

        // A_x from sh_x (packed bf16), element j = sign * x_b[qm^j]
        unsigned long long xq = sh_x[s & 3][bm];
        FragU Ax; Ax.w[2] = 0; Ax.w[3] = 0;
        {
          unsigned e0 = ((unsigned)(xq >> xsh[0]) & 0xffffu) ^ smx[0];
          unsigned e1 = ((unsigned)(xq >> xsh[1]) & 0xffffu) ^ smx[1];
          unsigned e2 = ((unsigned)(xq >> xsh[2]) & 0xffffu) ^ smx[2];
          unsigned e3 = ((unsigned)(xq >> xsh[3]) & 0xffffu) ^ smx[3];
          Ax.w[0] = (quad == 0) ? (e0 | (e1 << 16)) : 0u;
          Ax.w[1] = (quad == 0) ? (e2 | (e3 << 16)) : 0u;
        }
        f32x4 acc0 = {bias[0], bias[0], bias[0], bias[0]};
        f32x4 acc1 = {bias[1], bias[1], bias[1], bias[1]};
        acc0 = __builtin_amdgcn_mfma_f32_16x16x32_bf16(Ax.v, Bx[0].v, acc0, 0, 0, 0);
        acc1 = __builtin_amdgcn_mfma_f32_16x16x32_bf16(Ax.v, Bx[1].v, acc1, 0, 0, 0);
        #pragma unroll
        for (int ks = 0; ks < 8; ++ks) {
          FragU A;
          A.u = *(const uint4*)(hp + aoff[ks]);
          const unsigned m = smask[ks >> 1];
          A.w[0] ^= m; A.w[1] ^= m; A.w[2] ^= m; A.w[3] ^= m;
          acc0 = __builtin_amdgcn_mfma_f32_16x16x32_bf16(A.v, Bf[0 * 8 + ks].v, acc0, 0, 0, 0);
          acc1 = __builtin_amdgcn_mfma_f32_16x16x32_bf16(A.v, Bf[1 * 8 + ks].v, acc1, 0, 0, 0);
        }
        // intra-wave gate gather: partner = lane ^ 8 (other g of the pair)
        float o00 = __shfl_xor(acc0[0], 8, 64), o01 = __shfl_xor(acc0[1], 8, 64);
        float o02 = __shfl_xor(acc0[2], 8, 64), o03 = __shfl_xor(acc0[3], 8, 64);
        float o10 = __shfl_xor(acc1[0], 8, 64), o11 = __shfl_xor(acc1[1], 8, 64);
        float o12 = __shfl_xor(acc1[2], 8, 64), o13 = __shfl_xor(acc1[3], 8, 64);
        // lane handles b = s8*2 + e, col = quad*64 + u
        #pragma unroll
        for (int e = 0; e < 2; ++e) {
          float a0l = e ? acc0[1] : acc0[0], a0h = e ? acc0[3] : acc0[2];
          float a1l = e ? acc1[1] : acc1[0], a1h = e ? acc1[3] : acc1[2];
          float b0l = e ? o01 : o00, b0h = e ? o03 : o02;
          float b1l = e ? o11 : o10, b1h = e ? o13 : o12;
          float pf = s8 ? b0h : a0l;   // gate 0 (f)
          float pi = s8 ? a0h : b0l;   // gate 1 (i)
          float po = s8 ? b1h : a1l;   // gate 2 (o)
          float pc = s8 ? a1h : b1l;   // gate 3 (c)
          float fg = fast_sigmoid(pf), ig = fast_sigmoid(pi), og = fast_sigmoid(po);
          float cv = fast_tanh(pc);
          float cs = e ? cs1 : cs0;
          cs = ig * cv + fg * cs;
          if (e) cs1 = cs; else cs0 = cs;
          float h = og * fast_tanh(cs);
          *(unsigned short*)(hw + (s8 * 2 + e) * 544 + hw_off) = (unsigned short)f2bf(h);
        }
      }
      __syncthreads();
    }
  } else {
    // ================= HELPER WAVES (b = wv-8) =================
    const int b  = wv - 8;
    const int f  = lane & 3;
    const int ch = lane >> 2;                 // 16 chunks of 16 h
    float fw16[16];
    #pragma unroll
    for (int i = 0; i < 16; ++i) fw16[i] = fw[(ch * 16 + i) * 4 + f];
    const float fb0 = fb[0], fb1 = fb[1], fb2 = fb[2], fb3 = fb[3];

    // prologue: x slots 0,1
    if (lane == 0) {
      #pragma unroll
      for (int s0 = 0; s0 < 2; ++s0) {
        if (role == 0) {
          float4 xv = *(const float4*)(x_in + (size_t)((bg0 + b) * T_ + s0) * F_);
          sh_x[s0][b] = pack4bf(xv.x, xv.y, xv.z, xv.w);
        } else {
          unsigned long long v;
          while ((v = __hip_atomic_load(&g_inter_q[s0][bg0 + b], __ATOMIC_RELAXED,
                                        __HIP_MEMORY_SCOPE_AGENT)) == 0ull)
            __builtin_amdgcn_s_sleep(1);
          sh_x[s0][b] = v;
        }
      }
    }
    __syncthreads();

    for (int s = 0; s <= T_; ++s) {
      if (s >= 1 && (role == 0 || s == T_)) {
        const char* hb = (const char*)sh_h + ((s - 1) & 1) * 2176 + b * 544 + ch * 32;
        uint4 h0 = *(const uint4*)hb;
        uint4 h1 = *(const uint4*)(hb + 16);
        float p = 0.f;
        p += bfl(h0.x) * fw16[0];  p += bfh(h0.x) * fw16[1];
        p += bfl(h0.y) * fw16[2];  p += bfh(h0.y) * fw16[3];
        p += bfl(h0.z) * fw16[4];  p += bfh(h0.z) * fw16[5];
        p += bfl(h0.w) * fw16[6];  p += bfh(h0.w) * fw16[7];
        p += bfl(h1.x) * fw16[8];  p += bfh(h1.x) * fw16[9];
        p += bfl(h1.y) * fw16[10]; p += bfh(h1.y) * fw16[11];
        p += bfl(h1.z) * fw16[12]; p += bfh(h1.z) * fw16[13];
        p += bfl(h1.w) * fw16[14]; p += bfh(h1.w) * fw16[15];
        p += __shfl_xor(p, 4, 64);
        p += __shfl_xor(p, 8, 64);
        p += __shfl_xor(p, 16, 64);
        p += __shfl_xor(p, 32, 64);
        float p0 = __shfl(p, 0, 64), p1 = __shfl(p, 1, 64);
        float p2 = __shfl(p, 2, 64), p3 = __shfl(p, 3, 64);
        if (lane == 0) {
          p0 += fb0; p1 += fb1; p2 += fb2; p3 += fb3;
          float inv = 1.f / fmaxf(sqrtf(p0*p0 + p1*p1 + p2*p2 + p3*p3), 1e-12f);
          p0 *= inv; p1 *= inv; p2 *= inv; p3 *= inv;
          if (role == 0) {
            __hip_atomic_store(&g_inter_q[s - 1][bg0 + b], pack4bf(p0, p1, p2, p3),
                               __ATOMIC_RELAXED, __HIP_MEMORY_SCOPE_AGENT);
          } else if (s == T_) {
            *(float4*)(out_final + (bg0 + b) * F_) = make_float4(p0, p1, p2, p3);
          }
        }
      }
      if (s + 2 < T_ && lane == 0) {
        const int slot = (s + 2) & 3;
        if (role == 0) {
          float4 xv = *(const float4*)(x_in + (size_t)((bg0 + b) * T_ + s + 2) * F_);
          sh_x[slot][b] = pack4bf(xv.x, xv.y, xv.z, xv.w);
        } else {
          unsigned long long v;
          while ((v = __hip_atomic_load(&g_inter_q[s + 2][bg0 + b], __ATOMIC_RELAXED,
                                        __HIP_MEMORY_SCOPE_AGENT)) == 0ull)
            __builtin_amdgcn_s_sleep(1);
          sh_x[slot][b] = v;
        }
      }
      __syncthreads();
    }
  }
}

extern "C" void kernel_launch(void* const* d_in, const int* in_sizes, int n_in,
                              void* d_out, int out_size, void* d_ws, size_t ws_size,
                              hipStream_t stream) {
  const float* x   = (const float*)d_in[0];
  const float* wxr = (const float*)d_in[1];
  const float* wxi = (const float*)d_in[2];
  const float* wxj = (const float*)d_in[3];
  const float* wxk = (const float*)d_in[4];
  const float* wxb = (const float*)d_in[5];
  const float* uhr = (const float*)d_in[6];
  const float* uhi = (const float*)d_in[7];
  const float* uhj = (const float*)d_in[8];
  const float* uhk = (const float*)d_in[9];
  const float* fcw = (const float*)d_in[10];
  const float* fcb = (const float*)d_in[11];
  float* out = (float*)d_out;

  zero_inter<<<dim3(T_ * B_ / 256), dim3(256), 0, stream>>>();
  qlstm_fused<<<dim3(64), dim3(768), 0, stream>>>(
      x, uhr, uhi, uhj, uhk, wxr, wxi, wxj, wxk, wxb, fcw, fcb, out);
}

// Round 8
// 713.466 us; speedup vs baseline: 1.4865x; 1.3581x over previous
//
#include <hip/hip_runtime.h>

#define L_ 2
#define T_ 512
#define B_ 128
#define F_ 4
#define H_ 256
#define QSIGN_MASK 0x5390

typedef __attribute__((ext_vector_type(8))) short short8;
typedef __attribute__((ext_vector_type(4))) float f32x4;

// Mailbox: layer-0 normalized output, bf16x4 packed per (t,b); norm-1 => nonzero.
__device__ unsigned long long g_inter_q[T_][B_];

__global__ void zero_inter() {
  ((unsigned long long*)g_inter_q)[blockIdx.x * 256 + threadIdx.x] = 0ull;
}

__device__ __forceinline__ unsigned f2bf(float f) {
  unsigned u = __float_as_uint(f);
  return (u + 0x7fff + ((u >> 16) & 1)) >> 16;
}
__device__ __forceinline__ float fast_sigmoid(float x) { return 1.f / (1.f + __expf(-x)); }
__device__ __forceinline__ float fast_tanh(float x) {
  float a = fabsf(x), e = __expf(2.f * a);
  return copysignf(1.f - 2.f / (e + 1.f), x);
}
__device__ __forceinline__ unsigned long long pack4bf(float a, float b, float c, float d) {
  return (unsigned long long)f2bf(a)
       | ((unsigned long long)f2bf(b) << 16)
       | ((unsigned long long)f2bf(c) << 32)
       | ((unsigned long long)f2bf(d) << 48);
}

union FragU { short8 v; uint4 u; unsigned w[4]; };

// Grid = 64 WGs x 320 threads (5 waves). blockIdx<32: layer-0 producer; else layer-1.
// Compute waves 0-3: wave w owns cols u in [16w,16w+16). MFMA M rows = b*4+q
// (b=quad, q=reg in C/D), N = u16, one accumulator set per gate -> each lane holds
// all (q,g) for its (b,u): LSTM update fully in-lane, ZERO cross-lane ops, one
// barrier/step. Bias preloaded in acc; x-term = 1 MFMA per gate.
// Helper wave 4: projection via MFMA (P^T[f][b] = fw^T . h): lanes 0-3 get all 4
// components in-reg (no shuffles), publish mailbox every 2 steps (halves drains);
// x prefetch depth 2 into ring-4 sh_x.
__launch_bounds__(320, 1)
__global__ void qlstm_fused(const float* __restrict__ x_in,
                            const float* __restrict__ uhr, const float* __restrict__ uhi,
                            const float* __restrict__ uhj, const float* __restrict__ uhk,
                            const float* __restrict__ wxr, const float* __restrict__ wxi,
                            const float* __restrict__ wxj, const float* __restrict__ wxk,
                            const float* __restrict__ wxb_all,
                            const float* __restrict__ fcw_all, const float* __restrict__ fcb_all,
                            float* __restrict__ out_final)
{
  __shared__ __align__(16) unsigned short sh_h[2][4][272];  // double-buffered h (bf16)
  __shared__ unsigned long long sh_x[4][4];                 // ring-4 x, bf16x4 packed

  const int t     = threadIdx.x;
  const int role  = blockIdx.x >> 5;
  const int bg    = blockIdx.x & 31;
  const int bg0   = bg * 4;
  const int layer = role;
  const int wv    = t >> 6;
  const int lane  = t & 63;
  const int quad  = lane >> 4;
  const int sub   = lane & 15;

  const float* wb = wxb_all + layer * 4 * H_;
  const float* fw = fcw_all + layer * H_ * F_;
  const float* fb = fcb_all + layer * F_;

  for (int i = t; i < 2176; i += 320) ((unsigned short*)sh_h)[i] = 0;

  if (wv < 4) {
    // ================= COMPUTE WAVES =================
    const int u  = wv * 16 + sub;   // B n-col / D col
    const int ba = sub >> 2;        // A-side row -> batch
    const int qa = sub & 3;         // A-side row -> q

    // persistent B fragments [g][ks]: raw component blocks (d=ks>>1, p-half=ks&1)
    FragU Bf[32];
    FragU Bx[4];
    float bv[4][4];
    {
      const float* Cc[4] = {uhr, uhi, uhj, uhk};
      const float* Xc[4] = {wxr, wxi, wxj, wxk};
      #pragma unroll
      for (int g = 0; g < 4; ++g) {
        #pragma unroll
        for (int ks = 0; ks < 8; ++ks) {
          const int d  = ks >> 1;
          const int pp = (ks & 1) * 32 + quad * 8;
          const float* src = Cc[d] + (size_t)((layer * 4 + g) * 64 + pp) * 64 + u;
          FragU f;
          #pragma unroll
          for (int j = 0; j < 8; ++j) f.v[j] = (short)f2bf(src[j * 64]);
          Bf[g * 8 + ks] = f;
        }
        FragU fx; fx.w[0] = 0; fx.w[1] = 0; fx.w[2] = 0; fx.w[3] = 0;
        if (quad == 0) {
          unsigned e0 = f2bf(Xc[0][(layer * 4 + g) * 64 + u]);
          unsigned e1 = f2bf(Xc[1][(layer * 4 + g) * 64 + u]);
          unsigned e2 = f2bf(Xc[2][(layer * 4 + g) * 64 + u]);
          unsigned e3 = f2bf(Xc[3][(layer * 4 + g) * 64 + u]);
          fx.w[0] = e0 | (e1 << 16);
          fx.w[1] = e2 | (e3 << 16);
        }
        Bx[g] = fx;
        #pragma unroll
        for (int r = 0; r < 4; ++r) bv[g][r] = wb[g * 256 + r * 64 + u];
      }
    }
    // sign masks (a = qa^d) and A-read byte offsets
    unsigned smask[4], smx[4];
    int xsh[4], aoff[8];
    #pragma unroll
    for (int d = 0; d < 4; ++d) {
      const int a = qa ^ d;
      const bool neg = (QSIGN_MASK >> (a * 4 + qa)) & 1;
      smask[d] = neg ? 0x80008000u : 0u;
      smx[d]   = neg ? 0x8000u : 0u;
      xsh[d]   = 16 * a;
    }
    #pragma unroll
    for (int ks = 0; ks < 8; ++ks)
      aoff[ks] = ba * 544 + (((qa ^ (ks >> 1)) * 64 + (ks & 1) * 32 + quad * 8) << 1);
    float cs[4] = {0.f, 0.f, 0.f, 0.f};
    __syncthreads();

    const char* hbB = (const char*)sh_h;
    for (int s = 0; s <= T_; ++s) {
      if (s < T_) {
        const char* hp = hbB + ((s + 1) & 1) * 2176;   // h[s-1]
        // x A-frag: k=d (0..3), value = sign(a,q)*x[b][a], a=q^d
        unsigned long long xq = sh_x[s & 3][ba];
        FragU Ax; Ax.w[0] = 0; Ax.w[1] = 0; Ax.w[2] = 0; Ax.w[3] = 0;
        if (quad == 0) {
          unsigned e0 = ((unsigned)(xq >> xsh[0]) & 0xffffu) ^ smx[0];
          unsigned e1 = ((unsigned)(xq >> xsh[1]) & 0xffffu) ^ smx[1];
          unsigned e2 = ((unsigned)(xq >> xsh[2]) & 0xffffu) ^ smx[2];
          unsigned e3 = ((unsigned)(xq >> xsh[3]) & 0xffffu) ^ smx[3];
          Ax.w[0] = e0 | (e1 << 16);
          Ax.w[1] = e2 | (e3 << 16);
        }
        f32x4 acc0 = {bv[0][0], bv[0][1], bv[0][2], bv[0][3]};
        f32x4 acc1 = {bv[1][0], bv[1][1], bv[1][2], bv[1][3]};
        f32x4 acc2 = {bv[2][0], bv[2][1], bv[2][2], bv[2][3]};
        f32x4 acc3 = {bv[3][0], bv[3][1], bv[3][2], bv[3][3]};
        acc0 = __builtin_amdgcn_mfma_f32_16x16x32_bf16(Ax.v, Bx[0].v, acc0, 0, 0, 0);
        acc1 = __builtin_amdgcn_mfma_f32_16x16x32_bf16(Ax.v, Bx[1].v, acc1, 0, 0, 0);
        acc2 = __builtin_amdgcn_mfma_f32_16x16x32_bf16(Ax.v, Bx[2].v, acc2, 0, 0, 0);
        acc3 = __builtin_amdgcn_mfma_f32_16x16x32_bf16(Ax.v, Bx[3].v, acc3, 0, 0, 0);
        #pragma unroll
        for (int ks = 0; ks < 8; ++ks) {
          FragU A;
          A.u = *(const uint4*)(hp + aoff[ks]);
          const unsigned m = smask[ks >> 1];
          A.w[0] ^= m; A.w[1] ^= m; A.w[2] ^= m; A.w[3] ^= m;
          acc0 = __builtin_amdgcn_mfma_f32_16x16x32_bf16(A.v, Bf[0 * 8 + ks].v, acc0, 0, 0, 0);
          acc1 = __builtin_amdgcn_mfma_f32_16x16x32_bf16(A.v, Bf[1 * 8 + ks].v, acc1, 0, 0, 0);
          acc2 = __builtin_amdgcn_mfma_f32_16x16x32_bf16(A.v, Bf[2 * 8 + ks].v, acc2, 0, 0, 0);
          acc3 = __builtin_amdgcn_mfma_f32_16x16x32_bf16(A.v, Bf[3 * 8 + ks].v, acc3, 0, 0, 0);
        }
        // fully in-lane gates: b=quad, c = r*64+u for r=0..3
        char* hw = (char*)sh_h + (s & 1) * 2176 + quad * 544;
        #pragma unroll
        for (int r = 0; r < 4; ++r) {
          float fg = fast_sigmoid(acc0[r]);
          float ig = fast_sigmoid(acc1[r]);
          float og = fast_sigmoid(acc2[r]);
          float cv = fast_tanh(acc3[r]);
          cs[r] = ig * cv + fg * cs[r];
          float h = og * fast_tanh(cs[r]);
          *(unsigned short*)(hw + ((r * 64 + u) << 1)) = (unsigned short)f2bf(h);
        }
      }
      __syncthreads();
    }
  } else {
    // ================= HELPER WAVE =================
    // fw^T A-frags: A[m=f][k] = fw[k][f], rows 4-15 zero
    FragU Af[8];
    #pragma unroll
    for (int ks = 0; ks < 8; ++ks) {
      FragU f;
      #pragma unroll
      for (int j = 0; j < 8; ++j) {
        const int k = ks * 32 + quad * 8 + j;
        f.v[j] = (sub < 4) ? (short)f2bf(fw[k * 4 + sub]) : (short)0;
      }
      Af[ks] = f;
    }
    const float fb0 = fb[0], fb1 = fb[1], fb2 = fb[2], fb3 = fb[3];
    const int bl = sub & 3;   // B-side col (batch), clamped for lanes >= 4

    // prologue: x slots 0,1
    if (lane < 4) {
      #pragma unroll
      for (int s0 = 0; s0 < 2; ++s0) {
        if (role == 0) {
          float4 xv = *(const float4*)(x_in + (size_t)((bg0 + lane) * T_ + s0) * F_);
          sh_x[s0][lane] = pack4bf(xv.x, xv.y, xv.z, xv.w);
        } else {
          unsigned long long v;
          while ((v = __hip_atomic_load(&g_inter_q[s0][bg0 + lane], __ATOMIC_RELAXED,
                                        __HIP_MEMORY_SCOPE_AGENT)) == 0ull)
            __builtin_amdgcn_s_sleep(1);
          sh_x[s0][lane] = v;
        }
      }
    }
    unsigned long long heldq = 0ull;
    __syncthreads();

    for (int s = 0; s <= T_; ++s) {
      const bool doproj = (s >= 1) && (role == 0 || s == T_);
      if (doproj) {
        const char* hp = (const char*)sh_h + ((s + 1) & 1) * 2176;  // h[s-1]
        f32x4 pa = {fb0, fb1, fb2, fb3};
        #pragma unroll
        for (int ks = 0; ks < 8; ++ks) {
          FragU Bh;
          Bh.u = *(const uint4*)(hp + bl * 544 + ((ks * 32 + quad * 8) << 1));
          pa = __builtin_amdgcn_mfma_f32_16x16x32_bf16(Af[ks].v, Bh.v, pa, 0, 0, 0);
        }
        if (lane < 4) {   // quad==0, sub<4: all 4 components in-reg, batch = lane
          float p0 = pa[0], p1 = pa[1], p2 = pa[2], p3 = pa[3];
          float inv = 1.f / fmaxf(sqrtf(p0*p0 + p1*p1 + p2*p2 + p3*p3), 1e-12f);
          p0 *= inv; p1 *= inv; p2 *= inv; p3 *= inv;
          if (role == 0) {
            unsigned long long qw = pack4bf(p0, p1, p2, p3);
            if (s & 1) {
              heldq = qw;              // idx s-1 held one step
            } else {                   // publish pair (s-2, s-1): one drain per 2 steps
              __hip_atomic_store(&g_inter_q[s - 2][bg0 + lane], heldq,
                                 __ATOMIC_RELAXED, __HIP_MEMORY_SCOPE_AGENT);
              __hip_atomic_store(&g_inter_q[s - 1][bg0 + lane], qw,
                                 __ATOMIC_RELAXED, __HIP_MEMORY_SCOPE_AGENT);
            }
          } else {                     // consumer, s == T: final output
            *(float4*)(out_final + (bg0 + lane) * F_) = make_float4(p0, p1, p2, p3);
          }
        }
      }
      if (lane < 4 && s + 2 < T_) {
        const int slot = (s + 2) & 3;
        if (role == 0) {
          float4 xv = *(const float4*)(x_in + (size_t)((bg0 + lane) * T_ + s + 2) * F_);
          sh_x[slot][lane] = pack4bf(xv.x, xv.y, xv.z, xv.w);
        } else {
          unsigned long long v;
          while ((v = __hip_atomic_load(&g_inter_q[s + 2][bg0 + lane], __ATOMIC_RELAXED,
                                        __HIP_MEMORY_SCOPE_AGENT)) == 0ull)
            __builtin_amdgcn_s_sleep(1);
          sh_x[slot][lane] = v;
        }
      }
      __syncthreads();
    }
  }
}

extern "C" void kernel_launch(void* const* d_in, const int* in_sizes, int n_in,
                              void* d_out, int out_size, void* d_ws, size_t ws_size,
                              hipStream_t stream) {
  const float* x   = (const float*)d_in[0];
  const float* wxr = (const float*)d_in[1];
  const float* wxi = (const float*)d_in[2];
  const float* wxj = (const float*)d_in[3];
  const float* wxk = (const float*)d_in[4];
  const float* wxb = (const float*)d_in[5];
  const float* uhr = (const float*)d_in[6];
  const float* uhi = (const float*)d_in[7];
  const float* uhj = (const float*)d_in[8];
  const float* uhk = (const float*)d_in[9];
  const float* fcw = (const float*)d_in[10];
  const float* fcb = (const float*)d_in[11];
  float* out = (float*)d_out;

  zero_inter<<<dim3(T_ * B_ / 256), dim3(256), 0, stream>>>();
  qlstm_fused<<<dim3(64), dim3(320), 0, stream>>>(
      x, uhr, uhi, uhj, uhk, wxr, wxi, wxj, wxk, wxb, fcw, fcb, out);
}